// Round 3
// baseline (272.080 us; speedup 1.0000x reference)
//
#include <hip/hip_runtime.h>
#include <hip/hip_fp16.h>
#include <stdint.h>

typedef int i32x4 __attribute__((ext_vector_type(4)));

#define BM 256
#define BN 256
#define BK 128            // int8 elems (= bytes) per K-tile: m201 byte geometry
#define THREADS 512
#define SLOT 65536        // per-slot: A (2 kh x 16KB) + B (2 kh x 16KB)

__device__ __forceinline__ void gload_lds16(const void* g, void* l) {
  __builtin_amdgcn_global_load_lds(
      (const __attribute__((address_space(1))) unsigned int*)g,
      (__attribute__((address_space(3))) unsigned int*)l, 16, 0, 0);
}

// ---------------- quantize x: fp32(fp16 values) -> int8, grid-stride --------
__global__ __launch_bounds__(256) void quant_x_kernel(
    const float* __restrict__ x, const float* __restrict__ deltap,
    const float* __restrict__ zpp, int8_t* __restrict__ q, int n16) {
  const float rdelta = 1.0f / deltap[0];
  const float zp = zpp[0];
  for (int i = blockIdx.x * blockDim.x + threadIdx.x; i < n16;
       i += gridDim.x * blockDim.x) {
    const float4* src = (const float4*)x + (size_t)i * 4;
    int packed[4];
#pragma unroll
    for (int g = 0; g < 4; ++g) {
      float4 v = src[g];
      float f0 = fminf(127.f, fmaxf(-128.f, rintf(fmaf(v.x, rdelta, zp))));
      float f1 = fminf(127.f, fmaxf(-128.f, rintf(fmaf(v.y, rdelta, zp))));
      float f2 = fminf(127.f, fmaxf(-128.f, rintf(fmaf(v.z, rdelta, zp))));
      float f3 = fminf(127.f, fmaxf(-128.f, rintf(fmaf(v.w, rdelta, zp))));
      int q0 = (int)f0 & 255, q1 = (int)f1 & 255, q2 = (int)f2 & 255, q3 = (int)f3 & 255;
      packed[g] = q0 | (q1 << 8) | (q2 << 16) | (q3 << 24);
    }
    ((int4*)q)[i] = make_int4(packed[0], packed[1], packed[2], packed[3]);
  }
}

// ---------------- pack W: int32 -> int8, 16 elems/thread --------------------
__global__ __launch_bounds__(256) void pack_w_kernel(
    const int* __restrict__ w, int8_t* __restrict__ wp, int n16) {
  int i = blockIdx.x * blockDim.x + threadIdx.x;
  if (i >= n16) return;
  const int4* src = (const int4*)w + (size_t)i * 4;
  int packed[4];
#pragma unroll
  for (int g = 0; g < 4; ++g) {
    int4 v = src[g];
    packed[g] = (v.x & 255) | ((v.y & 255) << 8) | ((v.z & 255) << 16) | ((v.w & 255) << 24);
  }
  ((int4*)wp)[i] = make_int4(packed[0], packed[1], packed[2], packed[3]);
}

// ---------------- int8 GEMM, 256x256 tile, BK=128, 4-phase counted-vmcnt ----
// 8 waves (2M x 4N), per-wave 128x64 out, 64 MFMA/wave/K-tile (m201 density).
// LDS: 2 slots x 64KB; each slot = A[kh0]16K, A[kh1]16K, B[kh0]16K, B[kh1]16K,
// each region row-major [256][64B] with round-2 chunk swizzle
// (storage chunk = logical ^ ((row>>1)&3); inverse applied on global source).
// vmcnt(4) at phase-1/phase-3 ends: drains unit t(,1)/t+1(,0), keeps newest 4.
__global__ __launch_bounds__(THREADS, 2) void gemm_i8_kernel(
    const int8_t* __restrict__ Aq, const int8_t* __restrict__ Bw,
    const float* __restrict__ atwd, const float* __restrict__ zpws,
    const float* __restrict__ bias, float* __restrict__ out,
    int Mc, int Nc, int Kc) {
  __shared__ int8_t lds[2 * SLOT];

  // ---- T1 bijective XCD swizzle (nwg multiple of 8 here) ----
  const int nwg = gridDim.x;
  int bid = blockIdx.x;
  if ((nwg & 7) == 0) bid = (bid & 7) * (nwg >> 3) + (bid >> 3);
  const int nbn = Nc / BN;
  const int bm = bid / nbn;
  const int bn = bid % nbn;

  const int tid = threadIdx.x;
  const size_t K = (size_t)Kc;
  const int NT = Kc / BK;

  // ---- staging: sweep = 512 thr x 16B = 8KB = 128 rows x 64B (one kh) ----
  const int srow = tid >> 2;                        // 0..127
  const int lc = (tid & 3) ^ ((tid >> 3) & 3);      // inverse-swizzled chunk
  const int8_t* gA = Aq + ((size_t)(bm * BM + srow)) * K + lc * 16;
  const int8_t* gB = Bw + ((size_t)(bn * BN + srow)) * K + lc * 16;
  int8_t* lbase = &lds[tid * 16];
  const size_t row128 = (size_t)128 * K;

  auto stage = [&](int tt, int kh, int ab) {       // 2 gloads: one 16KB region
    const int8_t* g = ab ? gB : gA;
    int8_t* l = lbase + (tt & 1) * SLOT + ab * 32768 + kh * 16384;
    const size_t koff = (size_t)tt * BK + (size_t)kh * 64;
    gload_lds16(g + koff, l);
    gload_lds16(g + koff + row128, l + 8192);
  };

  // ---- fragment geometry ----
  const int lane = tid & 63;
  const int wave = tid >> 6;
  const int wr = wave >> 2;          // 0..1 -> 128 rows
  const int wc = wave & 3;           // 0..3 -> 64 cols
  const int fr = lane & 15;
  const int kc = lane >> 4;
  const int coff = ((kc ^ ((fr >> 1) & 3)) << 4);  // swizzled ds_read chunk
  const int aRow = wr * 128 + fr;
  const int bRow = wc * 64 + fr;

  i32x4 acc[8][4] = {};
  i32x4 afr[4], bfr[4];

#define READ_B(sb, kh)                                                        \
  _Pragma("unroll")                                                           \
  for (int j = 0; j < 4; ++j)                                                 \
    bfr[j] = *(const i32x4*)&lds[(sb) + 32768 + (kh)*16384 +                  \
                                 (bRow + j * 16) * 64 + coff];
#define READ_A(sb, mh, kh)                                                    \
  _Pragma("unroll")                                                           \
  for (int i = 0; i < 4; ++i)                                                 \
    afr[i] = *(const i32x4*)&lds[(sb) + (kh)*16384 +                          \
                                 (aRow + (mh)*64 + i * 16) * 64 + coff];
#define MFMA16(mh)                                                            \
  __builtin_amdgcn_s_setprio(1);                                             \
  _Pragma("unroll")                                                           \
  for (int i = 0; i < 4; ++i)                                                 \
    _Pragma("unroll")                                                         \
    for (int j = 0; j < 4; ++j)                                               \
      acc[(mh)*4 + i][j] =                                                    \
          __builtin_amdgcn_mfma_i32_16x16x64_i8(afr[i], bfr[j],               \
                                                acc[(mh)*4 + i][j], 0, 0, 0); \
  __builtin_amdgcn_s_setprio(0);
#define BAR __builtin_amdgcn_s_barrier()
#define LGKM0 asm volatile("s_waitcnt lgkmcnt(0)" ::: "memory")

  // ---- prologue: stage U(0,0), U(0,1); drain U(0,0), keep U(0,1) ----
  stage(0, 0, 0); stage(0, 0, 1);
  stage(0, 1, 0); stage(0, 1, 1);
  asm volatile("s_waitcnt vmcnt(4)" ::: "memory");
  BAR;

  for (int t = 0; t < NT; ++t) {
    const int sb = (t & 1) * SLOT;
    const bool pf = (t + 1 < NT);

    // ph0: frags(kh0, mh0) | stage U(t+1,0).A
    READ_B(sb, 0); READ_A(sb, 0, 0);
    if (pf) stage(t + 1, 0, 0);
    BAR; LGKM0; MFMA16(0); BAR;

    // ph1: frags(kh0, mh1) | stage U(t+1,0).B | drain U(t,1)
    READ_A(sb, 1, 0);
    if (pf) stage(t + 1, 0, 1);
    BAR; LGKM0; MFMA16(1);
    if (pf) asm volatile("s_waitcnt vmcnt(4)" ::: "memory");
    else    asm volatile("s_waitcnt vmcnt(0)" ::: "memory");
    BAR;

    // ph2: frags(kh1, mh0) | stage U(t+1,1).A
    READ_B(sb, 1); READ_A(sb, 0, 1);
    if (pf) stage(t + 1, 1, 0);
    BAR; LGKM0; MFMA16(0); BAR;

    // ph3: frags(kh1, mh1) | stage U(t+1,1).B | drain U(t+1,0)
    READ_A(sb, 1, 1);
    if (pf) stage(t + 1, 1, 1);
    BAR; LGKM0; MFMA16(1);
    if (pf) asm volatile("s_waitcnt vmcnt(4)" ::: "memory");
    BAR;
  }

  // ---- epilogue: C/D layout col=lane&15, row=(lane>>4)*4+reg ----
  const int r4 = (lane >> 4) << 2;
#pragma unroll
  for (int j = 0; j < 4; ++j) {
    const int cn = bn * BN + wc * 64 + j * 16 + fr;
    const float aw = atwd[cn];
    const float zs = zpws[cn];
    const float bs = bias[cn];
#pragma unroll
    for (int mi = 0; mi < 8; ++mi) {
      const size_t rbase = (size_t)(bm * BM + wr * 128 + mi * 16 + r4) * (size_t)Nc;
#pragma unroll
      for (int r = 0; r < 4; ++r) {
        float v = (float)acc[mi][j][r] * aw - zs + bs;
        v = __half2float(__float2half(v));  // match fp16 output rounding
        out[rbase + (size_t)r * Nc + cn] = v;
      }
    }
  }
#undef READ_B
#undef READ_A
#undef MFMA16
#undef BAR
#undef LGKM0
}

extern "C" void kernel_launch(void* const* d_in, const int* in_sizes, int n_in,
                              void* d_out, int out_size, void* d_ws, size_t ws_size,
                              hipStream_t stream) {
  const float* x         = (const float*)d_in[0];
  const float* act_delta = (const float*)d_in[1];
  const float* act_zp    = (const float*)d_in[2];
  const float* zpws      = (const float*)d_in[3];
  const float* atwd      = (const float*)d_in[4];
  const float* bias      = (const float*)d_in[5];
  const int*   w32       = (const int*)d_in[6];
  float* out = (float*)d_out;

  const int N = in_sizes[5];
  const int K = in_sizes[6] / N;
  const int M = in_sizes[0] / K;

  int8_t* q  = (int8_t*)d_ws;               // M*K bytes
  int8_t* wp = q + (size_t)M * K;           // N*K bytes

  {
    int n16 = (M * K) / 16;
    int grid = (n16 + 255) / 256;
    if (grid > 2048) grid = 2048;
    quant_x_kernel<<<grid, 256, 0, stream>>>(x, act_delta, act_zp, q, n16);
  }
  {
    int n16 = (N * K) / 16;
    pack_w_kernel<<<(n16 + 255) / 256, 256, 0, stream>>>(w32, wp, n16);
  }
  {
    dim3 grid((M / BM) * (N / BN));
    gemm_i8_kernel<<<grid, THREADS, 0, stream>>>(q, wp, atwd, zpws, bias, out, M, N, K);
  }
}

// Round 4
// 252.487 us; speedup vs baseline: 1.0776x; 1.0776x over previous
//
#include <hip/hip_runtime.h>
#include <hip/hip_fp16.h>
#include <stdint.h>

typedef int i32x4 __attribute__((ext_vector_type(4)));

#define BM 256
#define BN 256
#define BKB 64            // K-bytes (= int8 elems) per tile
#define NSLOT 4
#define SLOT_BYTES 32768  // A 16KB + B 16KB per slot
#define THREADS 512

__device__ __forceinline__ void gload_lds16(const void* g, void* l) {
  __builtin_amdgcn_global_load_lds(
      (const __attribute__((address_space(1))) unsigned int*)g,
      (__attribute__((address_space(3))) unsigned int*)l, 16, 0, 0);
}

// ---------------- quantize x: fp32(fp16 values) -> int8, grid-stride --------
__global__ __launch_bounds__(256) void quant_x_kernel(
    const float* __restrict__ x, const float* __restrict__ deltap,
    const float* __restrict__ zpp, int8_t* __restrict__ q, int n16) {
  const float rdelta = 1.0f / deltap[0];
  const float zp = zpp[0];
  for (int i = blockIdx.x * blockDim.x + threadIdx.x; i < n16;
       i += gridDim.x * blockDim.x) {
    const float4* src = (const float4*)x + (size_t)i * 4;
    int packed[4];
#pragma unroll
    for (int g = 0; g < 4; ++g) {
      float4 v = src[g];
      float f0 = fminf(127.f, fmaxf(-128.f, rintf(fmaf(v.x, rdelta, zp))));
      float f1 = fminf(127.f, fmaxf(-128.f, rintf(fmaf(v.y, rdelta, zp))));
      float f2 = fminf(127.f, fmaxf(-128.f, rintf(fmaf(v.z, rdelta, zp))));
      float f3 = fminf(127.f, fmaxf(-128.f, rintf(fmaf(v.w, rdelta, zp))));
      int q0 = (int)f0 & 255, q1 = (int)f1 & 255, q2 = (int)f2 & 255, q3 = (int)f3 & 255;
      packed[g] = q0 | (q1 << 8) | (q2 << 16) | (q3 << 24);
    }
    ((int4*)q)[i] = make_int4(packed[0], packed[1], packed[2], packed[3]);
  }
}

// ---------------- pack W: int32 -> int8, 16 elems/thread --------------------
__global__ __launch_bounds__(256) void pack_w_kernel(
    const int* __restrict__ w, int8_t* __restrict__ wp, int n16) {
  int i = blockIdx.x * blockDim.x + threadIdx.x;
  if (i >= n16) return;
  const int4* src = (const int4*)w + (size_t)i * 4;
  int packed[4];
#pragma unroll
  for (int g = 0; g < 4; ++g) {
    int4 v = src[g];
    packed[g] = (v.x & 255) | ((v.y & 255) << 8) | ((v.z & 255) << 16) | ((v.w & 255) << 24);
  }
  ((int4*)wp)[i] = make_int4(packed[0], packed[1], packed[2], packed[3]);
}

// ---------------- int8 GEMM, 256x256 tile, ONE barrier per K-tile -----------
// 8 waves (2M x 4N), per-wave 128x64 out, acc[8][4] i32x4.
// LDS: 4-slot rotation (4 x 32KB), prefetch depth 3.
// Per tile: {12 ds_read_b128 | 32 MFMA | 4 gloads U(t+3)} compiler-scheduled,
// then counted vmcnt(8) + s_barrier + sched_barrier(0). Never drains to 0 in
// steady state (AITER pattern). T2 chunk swizzle from round 2 (0 conflicts).
__global__ __launch_bounds__(THREADS, 2) void gemm_i8_kernel(
    const int8_t* __restrict__ Aq, const int8_t* __restrict__ Bw,
    const float* __restrict__ atwd, const float* __restrict__ zpws,
    const float* __restrict__ bias, float* __restrict__ out,
    int Mc, int Nc, int Kc) {
  __shared__ int8_t lds[NSLOT * SLOT_BYTES];

  // ---- T1 bijective XCD swizzle (nwg multiple of 8 here) ----
  const int nwg = gridDim.x;
  int bid = blockIdx.x;
  if ((nwg & 7) == 0) bid = (bid & 7) * (nwg >> 3) + (bid >> 3);
  const int nbn = Nc / BN;
  const int bm = bid / nbn;
  const int bn = bid % nbn;

  const int tid = threadIdx.x;
  const size_t K = (size_t)Kc;
  const int NT = Kc / BKB;

  // ---- staging: sweep = 512 thr x 16B = 8KB = 128 rows x 64B ----
  const int srow = tid >> 2;                        // 0..127
  const int lc = (tid & 3) ^ ((tid >> 3) & 3);      // inverse-swizzled chunk
  const int8_t* gA = Aq + ((size_t)(bm * BM + srow)) * K + lc * 16;
  const int8_t* gB = Bw + ((size_t)(bn * BN + srow)) * K + lc * 16;
  const size_t half_off = (size_t)128 * K;
  int8_t* ldst = &lds[tid * 16];

  auto stageA = [&](int t) {
    int8_t* l = ldst + (t & 3) * SLOT_BYTES;
    gload_lds16(gA + (size_t)t * BKB, l);
    gload_lds16(gA + (size_t)t * BKB + half_off, l + 8192);
  };
  auto stageB = [&](int t) {
    int8_t* l = ldst + (t & 3) * SLOT_BYTES + 16384;
    gload_lds16(gB + (size_t)t * BKB, l);
    gload_lds16(gB + (size_t)t * BKB + half_off, l + 8192);
  };

  // ---- fragment geometry ----
  const int lane = tid & 63;
  const int wave = tid >> 6;
  const int wr = wave >> 2;          // 0..1 -> 128 rows
  const int wc = wave & 3;           // 0..3 -> 64 cols
  const int fr = lane & 15;
  const int kc = lane >> 4;
  const int coff = ((kc ^ ((fr >> 1) & 3)) << 4);  // swizzled ds_read chunk
  const int aRow = wr * 128 + fr;
  const int bRow = wc * 64 + fr;

  i32x4 acc[8][4] = {};

  // ---- prologue: stage U(0),U(1),U(2); need U(0) -> keep 8 in flight ----
  stageA(0); stageB(0);
  if (NT > 1) { stageA(1); stageB(1); }
  if (NT > 2) { stageA(2); stageB(2); }
  if (NT > 2)      asm volatile("s_waitcnt vmcnt(8)" ::: "memory");
  else if (NT > 1) asm volatile("s_waitcnt vmcnt(4)" ::: "memory");
  else             asm volatile("s_waitcnt vmcnt(0)" ::: "memory");
  __builtin_amdgcn_s_barrier();
  __builtin_amdgcn_sched_barrier(0);

  for (int t = 0; t < NT; ++t) {
    const int8_t* sA = &lds[(t & 3) * SLOT_BYTES];
    const int8_t* sB = sA + 16384;

    i32x4 bfr[4], a0[4], a1[4];
#pragma unroll
    for (int j = 0; j < 4; ++j)
      bfr[j] = *(const i32x4*)&sB[(bRow + j * 16) * 64 + coff];
#pragma unroll
    for (int i = 0; i < 4; ++i)
      a0[i] = *(const i32x4*)&sA[(aRow + i * 16) * 64 + coff];
#pragma unroll
    for (int i = 0; i < 4; ++i)
      a1[i] = *(const i32x4*)&sA[(aRow + 64 + i * 16) * 64 + coff];

    if (t + 3 < NT) { stageA(t + 3); stageB(t + 3); }

#pragma unroll
    for (int i = 0; i < 4; ++i)
#pragma unroll
      for (int j = 0; j < 4; ++j)
        acc[i][j] = __builtin_amdgcn_mfma_i32_16x16x64_i8(a0[i], bfr[j], acc[i][j], 0, 0, 0);
#pragma unroll
    for (int i = 0; i < 4; ++i)
#pragma unroll
      for (int j = 0; j < 4; ++j)
        acc[4 + i][j] = __builtin_amdgcn_mfma_i32_16x16x64_i8(a1[i], bfr[j], acc[4 + i][j], 0, 0, 0);

    // ---- tile boundary: counted wait so U(t+1) is landed wave-locally,
    // barrier makes it collective. Steady state keeps 8 loads in flight.
    if (t < NT - 1) {
      if (t + 3 < NT)       asm volatile("s_waitcnt vmcnt(8)" ::: "memory");
      else if (t + 3 == NT) asm volatile("s_waitcnt vmcnt(4)" ::: "memory");
      else                  asm volatile("s_waitcnt vmcnt(0)" ::: "memory");
      __builtin_amdgcn_s_barrier();
      __builtin_amdgcn_sched_barrier(0);
    }
  }

  // ---- epilogue: C/D layout col=lane&15, row=(lane>>4)*4+reg.
  // j innermost so 4 consecutive stores cover 256B contiguous of one row.
  const int r4 = (lane >> 4) << 2;
  const int cn0 = bn * BN + wc * 64 + fr;
  float aw4[4], zs4[4], bs4[4];
#pragma unroll
  for (int j = 0; j < 4; ++j) {
    aw4[j] = atwd[cn0 + j * 16];
    zs4[j] = zpws[cn0 + j * 16];
    bs4[j] = bias[cn0 + j * 16];
  }
#pragma unroll
  for (int mi = 0; mi < 8; ++mi) {
#pragma unroll
    for (int r = 0; r < 4; ++r) {
      const size_t rbase = (size_t)(bm * BM + wr * 128 + mi * 16 + r4 + r) * (size_t)Nc;
#pragma unroll
      for (int j = 0; j < 4; ++j) {
        float v = (float)acc[mi][j][r] * aw4[j] - zs4[j] + bs4[j];
        v = __half2float(__float2half(v));  // match fp16 output rounding
        out[rbase + cn0 + j * 16] = v;
      }
    }
  }
}

extern "C" void kernel_launch(void* const* d_in, const int* in_sizes, int n_in,
                              void* d_out, int out_size, void* d_ws, size_t ws_size,
                              hipStream_t stream) {
  const float* x         = (const float*)d_in[0];
  const float* act_delta = (const float*)d_in[1];
  const float* act_zp    = (const float*)d_in[2];
  const float* zpws      = (const float*)d_in[3];
  const float* atwd      = (const float*)d_in[4];
  const float* bias      = (const float*)d_in[5];
  const int*   w32       = (const int*)d_in[6];
  float* out = (float*)d_out;

  const int N = in_sizes[5];
  const int K = in_sizes[6] / N;
  const int M = in_sizes[0] / K;

  int8_t* q  = (int8_t*)d_ws;               // M*K bytes
  int8_t* wp = q + (size_t)M * K;           // N*K bytes

  {
    int n16 = (M * K) / 16;
    int grid = (n16 + 255) / 256;
    if (grid > 2048) grid = 2048;
    quant_x_kernel<<<grid, 256, 0, stream>>>(x, act_delta, act_zp, q, n16);
  }
  {
    int n16 = (N * K) / 16;
    pack_w_kernel<<<(n16 + 255) / 256, 256, 0, stream>>>(w32, wp, n16);
  }
  {
    dim3 grid((M / BM) * (N / BN));
    gemm_i8_kernel<<<grid, THREADS, 0, stream>>>(q, wp, atwd, zpws, bias, out, M, N, K);
  }
}

// Round 5
// 247.377 us; speedup vs baseline: 1.0999x; 1.0207x over previous
//
#include <hip/hip_runtime.h>
#include <hip/hip_fp16.h>
#include <stdint.h>

typedef int i32x4 __attribute__((ext_vector_type(4)));

#define BM 128
#define BN 256
#define BKB 64            // K-bytes (= int8 elems) per tile
#define NSLOT 3
#define SLOT_BYTES 24576  // A 8KB + B 16KB per slot
#define THREADS 512

__device__ __forceinline__ void gload_lds16(const void* g, void* l) {
  __builtin_amdgcn_global_load_lds(
      (const __attribute__((address_space(1))) unsigned int*)g,
      (__attribute__((address_space(3))) unsigned int*)l, 16, 0, 0);
}

// ---------------- quantize x: fp32(fp16 values) -> int8, grid-stride --------
__global__ __launch_bounds__(256) void quant_x_kernel(
    const float* __restrict__ x, const float* __restrict__ deltap,
    const float* __restrict__ zpp, int8_t* __restrict__ q, int n16) {
  const float rdelta = 1.0f / deltap[0];
  const float zp = zpp[0];
  for (int i = blockIdx.x * blockDim.x + threadIdx.x; i < n16;
       i += gridDim.x * blockDim.x) {
    const float4* src = (const float4*)x + (size_t)i * 4;
    int packed[4];
#pragma unroll
    for (int g = 0; g < 4; ++g) {
      float4 v = src[g];
      float f0 = fminf(127.f, fmaxf(-128.f, rintf(fmaf(v.x, rdelta, zp))));
      float f1 = fminf(127.f, fmaxf(-128.f, rintf(fmaf(v.y, rdelta, zp))));
      float f2 = fminf(127.f, fmaxf(-128.f, rintf(fmaf(v.z, rdelta, zp))));
      float f3 = fminf(127.f, fmaxf(-128.f, rintf(fmaf(v.w, rdelta, zp))));
      int q0 = (int)f0 & 255, q1 = (int)f1 & 255, q2 = (int)f2 & 255, q3 = (int)f3 & 255;
      packed[g] = q0 | (q1 << 8) | (q2 << 16) | (q3 << 24);
    }
    ((int4*)q)[i] = make_int4(packed[0], packed[1], packed[2], packed[3]);
  }
}

// ---------------- pack W: int32 -> int8, 16 elems/thread --------------------
__global__ __launch_bounds__(256) void pack_w_kernel(
    const int* __restrict__ w, int8_t* __restrict__ wp, int n16) {
  int i = blockIdx.x * blockDim.x + threadIdx.x;
  if (i >= n16) return;
  const int4* src = (const int4*)w + (size_t)i * 4;
  int packed[4];
#pragma unroll
  for (int g = 0; g < 4; ++g) {
    int4 v = src[g];
    packed[g] = (v.x & 255) | ((v.y & 255) << 8) | ((v.z & 255) << 16) | ((v.w & 255) << 24);
  }
  ((int4*)wp)[i] = make_int4(packed[0], packed[1], packed[2], packed[3]);
}

// ---------------- int8 GEMM, 128x256 tile, 2 blocks/CU ----------------------
// 8 waves (2M x 4N), per-wave 64x64 out, acc[4][4] i32x4 (64 VGPR).
// __launch_bounds__(512,4): 4 waves/SIMD -> 2 resident blocks/CU; the second
// block fills the non-MFMA cycles (TLP, m97 mechanism).
// LDS: 3-slot rotation (3 x 24KB = 72KB/block, 144KB/CU), prefetch depth 2,
// steady-state vmcnt(3). One barrier per K-tile, compiler-scheduled interior.
// T2 chunk swizzle from round 2 (0 conflicts).
__global__ __launch_bounds__(THREADS, 4) void gemm_i8_kernel(
    const int8_t* __restrict__ Aq, const int8_t* __restrict__ Bw,
    const float* __restrict__ atwd, const float* __restrict__ zpws,
    const float* __restrict__ bias, float* __restrict__ out,
    int Mc, int Nc, int Kc) {
  __shared__ int8_t lds[NSLOT * SLOT_BYTES];

  // ---- T1 bijective XCD swizzle (nwg multiple of 8 here) ----
  const int nwg = gridDim.x;
  int bid = blockIdx.x;
  if ((nwg & 7) == 0) bid = (bid & 7) * (nwg >> 3) + (bid >> 3);
  const int nbn = Nc / BN;
  const int bm = bid / nbn;
  const int bn = bid % nbn;

  const int tid = threadIdx.x;
  const size_t K = (size_t)Kc;
  const int NT = Kc / BKB;

  // ---- staging: sweep = 512 thr x 16B = 8KB = 128 rows x 64B ----
  const int srow = tid >> 2;                        // 0..127
  const int lc = (tid & 3) ^ ((tid >> 3) & 3);      // inverse-swizzled chunk
  const int8_t* gA = Aq + ((size_t)(bm * BM + srow)) * K + lc * 16;
  const int8_t* gB = Bw + ((size_t)(bn * BN + srow)) * K + lc * 16;
  const size_t bHalf = (size_t)128 * K;
  int8_t* ldst = &lds[tid * 16];

  auto stage = [&](int t, int slot) {   // 3 gloads: A 8KB, B 2x8KB
    int8_t* l = ldst + slot * SLOT_BYTES;
    const size_t koff = (size_t)t * BKB;
    gload_lds16(gA + koff, l);
    gload_lds16(gB + koff, l + 8192);
    gload_lds16(gB + koff + bHalf, l + 16384);
  };

  // ---- fragment geometry ----
  const int lane = tid & 63;
  const int wave = tid >> 6;
  const int wr = wave >> 2;          // 0..1 -> 64 rows
  const int wc = wave & 3;           // 0..3 -> 64 cols
  const int fr = lane & 15;
  const int kc = lane >> 4;
  const int coff = ((kc ^ ((fr >> 1) & 3)) << 4);  // swizzled ds_read chunk
  const int aRow = wr * 64 + fr;
  const int bRow = wc * 64 + fr;

  i32x4 acc[4][4] = {};

  // ---- prologue: stage U(0),U(1); drain U(0) (keep 3 in flight) ----
  stage(0, 0);
  if (NT > 1) stage(1, 1);
  if (NT > 1) asm volatile("s_waitcnt vmcnt(3)" ::: "memory");
  else        asm volatile("s_waitcnt vmcnt(0)" ::: "memory");
  __builtin_amdgcn_s_barrier();
  __builtin_amdgcn_sched_barrier(0);

  int rs = 0;  // read slot for tile t
  for (int t = 0; t < NT; ++t) {
    const int8_t* sA = &lds[rs * SLOT_BYTES];
    const int8_t* sB = sA + 8192;

    i32x4 afr[4], bfr[4];
#pragma unroll
    for (int j = 0; j < 4; ++j)
      bfr[j] = *(const i32x4*)&sB[(bRow + j * 16) * 64 + coff];
#pragma unroll
    for (int i = 0; i < 4; ++i)
      afr[i] = *(const i32x4*)&sA[(aRow + i * 16) * 64 + coff];

    if (t + 2 < NT) {
      int ws = rs + 2; if (ws >= NSLOT) ws -= NSLOT;
      stage(t + 2, ws);
    }

#pragma unroll
    for (int i = 0; i < 4; ++i)
#pragma unroll
      for (int j = 0; j < 4; ++j)
        acc[i][j] = __builtin_amdgcn_mfma_i32_16x16x64_i8(afr[i], bfr[j], acc[i][j], 0, 0, 0);

    // ---- tile boundary: counted wait (U(t+1) landed), collective barrier ----
    if (t < NT - 1) {
      if (t + 2 < NT) asm volatile("s_waitcnt vmcnt(3)" ::: "memory");
      else            asm volatile("s_waitcnt vmcnt(0)" ::: "memory");
      __builtin_amdgcn_s_barrier();
      __builtin_amdgcn_sched_barrier(0);
    }
    rs = rs + 1; if (rs >= NSLOT) rs -= NSLOT;
  }

  // ---- epilogue: C/D layout col=lane&15, row=(lane>>4)*4+reg.
  // j innermost: 4 consecutive stores cover 4x16 floats of one row.
  const int r4 = (lane >> 4) << 2;
  const int cn0 = bn * BN + wc * 64 + fr;
  float aw4[4], zs4[4], bs4[4];
#pragma unroll
  for (int j = 0; j < 4; ++j) {
    aw4[j] = atwd[cn0 + j * 16];
    zs4[j] = zpws[cn0 + j * 16];
    bs4[j] = bias[cn0 + j * 16];
  }
#pragma unroll
  for (int mi = 0; mi < 4; ++mi) {
#pragma unroll
    for (int r = 0; r < 4; ++r) {
      const size_t rbase = (size_t)(bm * BM + wr * 64 + mi * 16 + r4 + r) * (size_t)Nc;
#pragma unroll
      for (int j = 0; j < 4; ++j) {
        float v = (float)acc[mi][j][r] * aw4[j] - zs4[j] + bs4[j];
        v = __half2float(__float2half(v));  // match fp16 output rounding
        out[rbase + cn0 + j * 16] = v;
      }
    }
  }
}

extern "C" void kernel_launch(void* const* d_in, const int* in_sizes, int n_in,
                              void* d_out, int out_size, void* d_ws, size_t ws_size,
                              hipStream_t stream) {
  const float* x         = (const float*)d_in[0];
  const float* act_delta = (const float*)d_in[1];
  const float* act_zp    = (const float*)d_in[2];
  const float* zpws      = (const float*)d_in[3];
  const float* atwd      = (const float*)d_in[4];
  const float* bias      = (const float*)d_in[5];
  const int*   w32       = (const int*)d_in[6];
  float* out = (float*)d_out;

  const int N = in_sizes[5];
  const int K = in_sizes[6] / N;
  const int M = in_sizes[0] / K;

  int8_t* q  = (int8_t*)d_ws;               // M*K bytes
  int8_t* wp = q + (size_t)M * K;           // N*K bytes

  {
    int n16 = (M * K) / 16;
    int grid = (n16 + 255) / 256;
    if (grid > 2048) grid = 2048;
    quant_x_kernel<<<grid, 256, 0, stream>>>(x, act_delta, act_zp, q, n16);
  }
  {
    int n16 = (N * K) / 16;
    pack_w_kernel<<<(n16 + 255) / 256, 256, 0, stream>>>(w32, wp, n16);
  }
  {
    dim3 grid((M / BM) * (N / BN));
    gemm_i8_kernel<<<grid, THREADS, 0, stream>>>(q, wp, atwd, zpws, bias, out, M, N, K);
  }
}